// Round 4
// baseline (532.187 us; speedup 1.0000x reference)
//
#include <hip/hip_runtime.h>
#include <hip/hip_cooperative_groups.h>
#include <math.h>

namespace cg = cooperative_groups;

#define NN 512     // N_NODES
#define SD 32      // STATE_DIM == MESSAGE_DIM
#define HM 64      // H_MSG

typedef __bf16 bf16x8 __attribute__((ext_vector_type(8)));
typedef float floatx4 __attribute__((ext_vector_type(4)));

struct KParams {
    const float *J, *b, *mpW1, *mpb1, *mpW2, *mpb2, *mpW3, *mpb3;
    const float *Wih, *Whh, *bih, *bhh;
    const float *rW1, *rb1, *rW2, *rb2, *rW3, *rb3;
    float *out;
    float *JT;          // 512x512 transposed J
    float *hb0, *hb1;   // hip double buffers (512x64)
};

__device__ __forceinline__ float sigmoidf_(float x) {
    return 1.0f / (1.0f + __expf(-x));
}

// One cooperative kernel, 256 blocks x 512 threads. Block owns nodes
// j0=2*bid, j1=2*bid+1. Waves 0-3 -> j0, waves 4-7 -> j1; each wave covers
// 128 source rows in 8 groups of 16. Cross-block data = hip[] only
// (double-buffered, one grid.sync per step). h, hjp live in block LDS.
// 256 blocks => cooperative co-residency needs only 1 block/CU (safe).
__global__ __launch_bounds__(512, 2) void fused_kernel(KParams p)
{
    __shared__ __align__(16) float m2f[8][16][68];  // per-wave GEMM1->GEMM2 transpose buf
    __shared__ float msum[8][32];
    __shared__ float hjpS[2][64];
    __shared__ float hS[2][32];
    __shared__ float msgS[2][32];
    __shared__ float giS[2][96], ghS[2][96];

    cg::grid_group grid = cg::this_grid();

    const int tid  = threadIdx.x;
    const int lane = tid & 63;
    const int wave = tid >> 6;       // 0..7
    const int nsel = wave >> 2;      // node select 0/1
    const int nw   = wave & 3;       // wave-within-node
    const int j    = blockIdx.x * 2 + nsel;   // this wave's destination node
    const int q    = lane >> 4;      // k-quad
    const int c    = lane & 15;      // A-row (edge) / C-col index

    // ---------------- prep phase ----------------
    if (tid < 128) {   // h==0 projections for nodes j0, j1
        int node = tid >> 6, cc = tid & 63;
        int jj = blockIdx.x * 2 + node;
        const float* wr = p.mpW1 + cc * 67;
        float bj = p.b[jj];
        p.hb0[jj * HM + cc] = bj * wr[65];
        hjpS[node][cc] = bj * wr[66] + p.mpb1[cc];
    }
    {   // J transpose: one 32x32 tile per block (256 tiles), m2f as scratch
        float* tile = (float*)m2f;  // 32x33
        int bx = blockIdx.x & 15, by = blockIdx.x >> 4;
        int tx = tid & 31, ty = tid >> 5;   // ty 0..15
        #pragma unroll
        for (int r = 0; r < 32; r += 16)
            tile[(ty + r) * 33 + tx] = p.J[(by * 32 + ty + r) * NN + bx * 32 + tx];
        __syncthreads();
        #pragma unroll
        for (int r = 0; r < 32; r += 16)
            p.JT[(bx * 32 + ty + r) * NN + by * 32 + tx] = tile[tx * 33 + ty + r];
        __syncthreads();   // m2f scratch free again
    }

    // ---------------- per-thread persistent preloads (f32 -> bf16 in regs) --
    float wj_r[16], b2v[4], b3v[2];
    #pragma unroll
    for (int s = 0; s < 8; ++s) {
        wj_r[s]     = p.mpW1[(q * 8 + s) * 67 + 64];
        wj_r[8 + s] = p.mpW1[(q * 8 + s + 32) * 67 + 64];
    }
    #pragma unroll
    for (int t4 = 0; t4 < 4; ++t4) b2v[t4] = p.mpb2[t4 * 16 + c];
    #pragma unroll
    for (int t2 = 0; t2 < 2; ++t2) b3v[t2] = p.mpb3[t2 * 16 + c];

    bf16x8 Bw2[2][4], Bw3[2][2];
    #pragma unroll
    for (int f = 0; f < 2; ++f)
        #pragma unroll
        for (int t4 = 0; t4 < 4; ++t4) {
            const float* src = p.mpW2 + (t4 * 16 + c) * 64 + f * 32 + q * 8;
            bf16x8 v;
            #pragma unroll
            for (int s = 0; s < 8; ++s) v[s] = (__bf16)src[s];
            Bw2[f][t4] = v;
        }
    #pragma unroll
    for (int f = 0; f < 2; ++f)
        #pragma unroll
        for (int t2 = 0; t2 < 2; ++t2) {
            const float* src = p.mpW3 + (t2 * 16 + c) * 64 + f * 32 + q * 8;
            bf16x8 v;
            #pragma unroll
            for (int s = 0; s < 8; ++s) v[s] = (__bf16)src[s];
            Bw3[f][t2] = v;
        }

    __threadfence();
    grid.sync();

    // J column j, this wave's 128 rows (2 values/lane)
    const float jA = p.JT[j * NN + nw * 128 + lane];
    const float jB = p.JT[j * NN + nw * 128 + 64 + lane];

    const floatx4 zero4 = {0.f, 0.f, 0.f, 0.f};

    // ---------------- 5 message-passing steps ----------------
    for (int t = 0; t < 5; ++t) {
        const float* hb_read = (t & 1) ? p.hb1 : p.hb0;
        float*       hb_next = (t & 1) ? p.hb0 : p.hb1;

        // ---- edge phase ----
        float hjp_r[16];
        #pragma unroll
        for (int s = 0; s < 8; ++s) {
            hjp_r[s]     = hjpS[nsel][q * 8 + s];
            hjp_r[8 + s] = hjpS[nsel][q * 8 + s + 32];
        }
        float accf[2][4];
        #pragma unroll
        for (int t2 = 0; t2 < 2; ++t2)
            #pragma unroll
            for (int r = 0; r < 4; ++r) accf[t2][r] = 0.0f;

        const float4* hp = (const float4*)(hb_read + (nw * 128 + c) * 64);
        float4 nh0 = hp[q * 2];
        float4 nh1 = hp[q * 2 + 1];
        float4 nh2 = hp[q * 2 + 8];
        float4 nh3 = hp[q * 2 + 9];

        #pragma unroll
        for (int g = 0; g < 8; ++g) {
            float4 h0 = nh0, h1 = nh1, h2 = nh2, h3 = nh3;
            if (g < 7) {
                const float4* np = (const float4*)(hb_read + (nw * 128 + (g + 1) * 16 + c) * 64);
                nh0 = np[q * 2];
                nh1 = np[q * 2 + 1];
                nh2 = np[q * 2 + 8];
                nh3 = np[q * 2 + 9];
            }
            float Jv = __shfl((g < 4) ? jA : jB, (g & 3) * 16 + c);

            float va[16];
            va[0]  = h0.x; va[1]  = h0.y; va[2]  = h0.z; va[3]  = h0.w;
            va[4]  = h1.x; va[5]  = h1.y; va[6]  = h1.z; va[7]  = h1.w;
            va[8]  = h2.x; va[9]  = h2.y; va[10] = h2.z; va[11] = h2.w;
            va[12] = h3.x; va[13] = h3.y; va[14] = h3.z; va[15] = h3.w;

            bf16x8 a0, a1;
            #pragma unroll
            for (int s = 0; s < 8; ++s) {
                float v0 = fmaf(Jv, wj_r[s],     va[s]     + hjp_r[s]);
                float v1 = fmaf(Jv, wj_r[8 + s], va[8 + s] + hjp_r[8 + s]);
                a0[s] = (__bf16)fmaxf(v0, 0.0f);
                a1[s] = (__bf16)fmaxf(v1, 0.0f);
            }

            // GEMM1: C layout row=q*4+r (edge), col=t4*16+c (ch)
            floatx4 c1[4];
            #pragma unroll
            for (int t4 = 0; t4 < 4; ++t4) {
                c1[t4] = __builtin_amdgcn_mfma_f32_16x16x32_bf16(a0, Bw2[0][t4], zero4, 0, 0, 0);
                c1[t4] = __builtin_amdgcn_mfma_f32_16x16x32_bf16(a1, Bw2[1][t4], c1[t4], 0, 0, 0);
            }

            // bias+relu -> per-wave LDS transpose (f32, conflict-free)
            #pragma unroll
            for (int t4 = 0; t4 < 4; ++t4)
                #pragma unroll
                for (int r = 0; r < 4; ++r)
                    m2f[wave][q * 4 + r][t4 * 16 + c] = fmaxf(c1[t4][r] + b2v[t4], 0.0f);

            asm volatile("s_waitcnt lgkmcnt(0)" ::: "memory");  // same-wave RAW

            float4 ra0 = *(const float4*)&m2f[wave][c][q * 8];
            float4 ra1 = *(const float4*)&m2f[wave][c][q * 8 + 4];
            float4 ra2 = *(const float4*)&m2f[wave][c][q * 8 + 32];
            float4 ra3 = *(const float4*)&m2f[wave][c][q * 8 + 36];

            bf16x8 a2, a3;
            a2[0] = (__bf16)ra0.x; a2[1] = (__bf16)ra0.y; a2[2] = (__bf16)ra0.z; a2[3] = (__bf16)ra0.w;
            a2[4] = (__bf16)ra1.x; a2[5] = (__bf16)ra1.y; a2[6] = (__bf16)ra1.z; a2[7] = (__bf16)ra1.w;
            a3[0] = (__bf16)ra2.x; a3[1] = (__bf16)ra2.y; a3[2] = (__bf16)ra2.z; a3[3] = (__bf16)ra2.w;
            a3[4] = (__bf16)ra3.x; a3[5] = (__bf16)ra3.y; a3[6] = (__bf16)ra3.z; a3[7] = (__bf16)ra3.w;

            floatx4 c2[2];
            #pragma unroll
            for (int t2 = 0; t2 < 2; ++t2) {
                c2[t2] = __builtin_amdgcn_mfma_f32_16x16x32_bf16(a2, Bw3[0][t2], zero4, 0, 0, 0);
                c2[t2] = __builtin_amdgcn_mfma_f32_16x16x32_bf16(a3, Bw3[1][t2], c2[t2], 0, 0, 0);
            }
            #pragma unroll
            for (int t2 = 0; t2 < 2; ++t2)
                #pragma unroll
                for (int r = 0; r < 4; ++r)
                    accf[t2][r] += fmaxf(c2[t2][r] + b3v[t2], 0.0f);

            asm volatile("s_waitcnt lgkmcnt(0)" ::: "memory");  // WAR before next writes
        }

        // column sums -> msum
        float s0 = accf[0][0] + accf[0][1] + accf[0][2] + accf[0][3];
        float s1 = accf[1][0] + accf[1][1] + accf[1][2] + accf[1][3];
        s0 += __shfl_xor(s0, 16); s0 += __shfl_xor(s0, 32);
        s1 += __shfl_xor(s1, 16); s1 += __shfl_xor(s1, 32);
        if (lane < 16) {
            msum[wave][c]      = s0;
            msum[wave][16 + c] = s1;
        }
        __syncthreads();

        // ---- block-local tail for both nodes ----
        if (tid < 64) {
            int node = tid >> 5, d = tid & 31;
            msgS[node][d] = msum[node * 4 + 0][d] + msum[node * 4 + 1][d] +
                            msum[node * 4 + 2][d] + msum[node * 4 + 3][d];
        }
        __syncthreads();

        if (tid < 192) {
            int node = tid / 96, r = tid % 96;
            int g = r >> 5, d = r & 31;
            const float* wi = p.Wih + (g * 32 + d) * 64;
            float a  = p.bih[g * 32 + d];
            float bb = p.bhh[g * 32 + d];
            if (t > 0) {
                const float* wh = p.Whh + (g * 32 + d) * 32;
                #pragma unroll
                for (int k = 0; k < 32; ++k) {
                    float hv = hS[node][k];
                    a  = fmaf(hv, wi[k], a);
                    bb = fmaf(hv, wh[k], bb);
                }
            }
            #pragma unroll
            for (int k = 0; k < 32; ++k) a = fmaf(msgS[node][k], wi[32 + k], a);
            giS[node][r] = a; ghS[node][r] = bb;
        }
        __syncthreads();

        if (tid < 64) {
            int node = tid >> 5, d = tid & 31;
            float r  = sigmoidf_(giS[node][d] + ghS[node][d]);
            float z  = sigmoidf_(giS[node][32 + d] + ghS[node][32 + d]);
            float ng = tanhf(giS[node][64 + d] + r * ghS[node][64 + d]);
            float hold = (t > 0) ? hS[node][d] : 0.0f;
            hS[node][d] = (1.0f - z) * ng + z * hold;
        }
        __syncthreads();

        if (t < 4) {
            // projections for next step (both nodes)
            if (tid < 128) {
                int node = tid >> 6, cc = tid & 63;
                int jj = blockIdx.x * 2 + node;
                const float* wr = p.mpW1 + cc * 67;
                float bj = p.b[jj];
                float si = bj * wr[65];
                float sj = bj * wr[66] + p.mpb1[cc];
                #pragma unroll
                for (int d = 0; d < 32; ++d) {
                    float hv = hS[node][d];
                    si = fmaf(hv, wr[d], si);
                    sj = fmaf(hv, wr[32 + d], sj);
                }
                hb_next[jj * HM + cc] = si;
                hjpS[node][cc] = sj;
            }
            __threadfence();
            grid.sync();
        } else {
            // readout: wave 0 -> node 0, wave 1 -> node 1
            if (wave < 2) {
                int node = wave;
                int jj = blockIdx.x * 2 + node;
                float y1 = p.rb1[lane];
                #pragma unroll
                for (int k = 0; k < 32; ++k) y1 = fmaf(hS[node][k], p.rW1[lane * 32 + k], y1);
                y1 = fmaxf(y1, 0.0f);
                float y2 = p.rb2[lane];
                #pragma unroll
                for (int k = 0; k < 64; ++k) y2 = fmaf(__shfl(y1, k), p.rW2[lane * 64 + k], y2);
                y2 = fmaxf(y2, 0.0f);
                float y3 = (lane < 2) ? p.rb3[lane] : 0.0f;
                #pragma unroll
                for (int k = 0; k < 64; ++k) {
                    float v = __shfl(y2, k);
                    if (lane < 2) y3 = fmaf(v, p.rW3[lane * 64 + k], y3);
                }
                if (lane < 2) p.out[jj * 2 + lane] = sigmoidf_(y3);
            }
        }
    }
}

// ---------------------------------------------------------------------------
extern "C" void kernel_launch(void* const* d_in, const int* in_sizes, int n_in,
                              void* d_out, int out_size, void* d_ws, size_t ws_size,
                              hipStream_t stream)
{
    float* ws = (float*)d_ws;

    KParams p;
    p.J    = (const float*)d_in[0];
    p.b    = (const float*)d_in[1];
    p.mpW1 = (const float*)d_in[2];
    p.mpb1 = (const float*)d_in[3];
    p.mpW2 = (const float*)d_in[4];
    p.mpb2 = (const float*)d_in[5];
    p.mpW3 = (const float*)d_in[6];
    p.mpb3 = (const float*)d_in[7];
    p.Wih  = (const float*)d_in[8];
    p.Whh  = (const float*)d_in[9];
    p.bih  = (const float*)d_in[10];
    p.bhh  = (const float*)d_in[11];
    p.rW1  = (const float*)d_in[12];
    p.rb1  = (const float*)d_in[13];
    p.rW2  = (const float*)d_in[14];
    p.rb2  = (const float*)d_in[15];
    p.rW3  = (const float*)d_in[16];
    p.rb3  = (const float*)d_in[17];
    p.out  = (float*)d_out;

    p.JT   = ws;                          // 512*512 f32
    p.hb0  = ws + 262144;                 // 512*64 f32
    p.hb1  = ws + 294912;                 // 512*64 f32

    void* kargs[] = { &p };
    hipLaunchCooperativeKernel((const void*)fused_kernel, dim3(NN / 2), dim3(512),
                               kargs, 0, stream);
}

// Round 5
// 220.764 us; speedup vs baseline: 2.4107x; 2.4107x over previous
//
#include <hip/hip_runtime.h>
#include <math.h>

#define NN 512     // N_NODES
#define SD 32      // STATE_DIM == MESSAGE_DIM
#define HM 64      // H_MSG
#define NB 256     // blocks

typedef __bf16 bf16x8 __attribute__((ext_vector_type(8)));
typedef float floatx4 __attribute__((ext_vector_type(4)));

struct KParams {
    const float *J, *b, *mpW1, *mpb1, *mpW2, *mpb2, *mpW3, *mpb3;
    const float *Wih, *Whh, *bih, *bhh;
    const float *rW1, *rb1, *rW2, *rb2, *rW3, *rb3;
    float *out;
    float *hb0, *hb1;   // hip double buffers (512x64 f32), exchanged at LLC
    unsigned *bar;      // [0]=arrival count (monotonic), [1]=generation
};

__device__ __forceinline__ float sigmoidf_(float x) {
    return 1.0f / (1.0f + __expf(-x));
}

// ---- coherence-point primitives (no L2 cache maintenance anywhere) --------
__device__ __forceinline__ unsigned ld_bypass_u32(const unsigned* p) {
    unsigned r;
    asm volatile("global_load_dword %0, %1, off sc0 sc1\n\ts_waitcnt vmcnt(0)"
                 : "=v"(r) : "v"(p) : "memory");
    return r;
}
// issue 4x16B bypass loads (one group's A-operand rows), no wait
__device__ __forceinline__ void issue4(const float* base,
        floatx4& a, floatx4& b, floatx4& c, floatx4& d) {
    asm volatile(
        "global_load_dwordx4 %0, %4, off sc0 sc1\n\t"
        "global_load_dwordx4 %1, %4, off offset:16 sc0 sc1\n\t"
        "global_load_dwordx4 %2, %4, off offset:128 sc0 sc1\n\t"
        "global_load_dwordx4 %3, %4, off offset:144 sc0 sc1"
        : "=&v"(a), "=&v"(b), "=&v"(c), "=&v"(d) : "v"(base));
}
__device__ __forceinline__ void wait4_4(floatx4& a, floatx4& b, floatx4& c, floatx4& d) {
    asm volatile("s_waitcnt vmcnt(4)" : "+v"(a), "+v"(b), "+v"(c), "+v"(d));
}
__device__ __forceinline__ void wait4_0(floatx4& a, floatx4& b, floatx4& c, floatx4& d) {
    asm volatile("s_waitcnt vmcnt(0)" : "+v"(a), "+v"(b), "+v"(c), "+v"(d));
}

// monotonic sense barrier: count via atomicAdd (LLC), gen via atomicMax,
// poll via bypass loads. round is 1-based; target = round*NB.
__device__ __forceinline__ void xbarrier(unsigned* bar, unsigned round) {
    __syncthreads();   // drains each wave's vmcnt (incl. atomicExch h-stores)
    if (threadIdx.x == 0) {
        unsigned old = atomicAdd(&bar[0], 1u);
        if (old + 1u == round * NB) {
            atomicMax(&bar[1], round);
        } else {
            while (ld_bypass_u32(&bar[1]) < round) __builtin_amdgcn_s_sleep(2);
        }
    }
    __syncthreads();
}

// One cooperative kernel, 256 blocks x 512 threads; block owns nodes
// j0=2*bid, j1=2*bid+1 (waves 0-3 / 4-7). Cross-block data = hip[] only:
// producers atomicExch (coherence point), consumers sc0sc1 bypass loads,
// custom barrier between steps. h/hjp block-local in LDS.
__global__ __launch_bounds__(512, 2) void fused_kernel(KParams p)
{
    __shared__ __align__(16) float m2f[8][16][68];
    __shared__ float msum[8][32];
    __shared__ float hjpS[2][64];
    __shared__ float hS[2][32];
    __shared__ float msgS[2][32];
    __shared__ float giS[2][96], ghS[2][96];

    const int tid  = threadIdx.x;
    const int lane = tid & 63;
    const int wave = tid >> 6;       // 0..7
    const int nsel = wave >> 2;      // node select
    const int nw   = wave & 3;       // wave-within-node
    const int j    = blockIdx.x * 2 + nsel;
    const int q    = lane >> 4;
    const int c    = lane & 15;

    // ---------------- prep: h==0 projections for own nodes ----------------
    if (tid < 128) {
        int node = tid >> 6, cc = tid & 63;
        int jj = blockIdx.x * 2 + node;
        const float* wr = p.mpW1 + cc * 67;
        float bj = p.b[jj];
        hjpS[node][cc] = bj * wr[66] + p.mpb1[cc];
        atomicExch(&p.hb0[jj * HM + cc], bj * wr[65]);   // hip0 -> LLC
    }

    // ---------------- persistent per-lane preloads ----------------
    float wj_r[16], b2v[4], b3v[2];
    #pragma unroll
    for (int s = 0; s < 8; ++s) {
        wj_r[s]     = p.mpW1[(q * 8 + s) * 67 + 64];
        wj_r[8 + s] = p.mpW1[(q * 8 + s + 32) * 67 + 64];
    }
    #pragma unroll
    for (int t4 = 0; t4 < 4; ++t4) b2v[t4] = p.mpb2[t4 * 16 + c];
    #pragma unroll
    for (int t2 = 0; t2 < 2; ++t2) b3v[t2] = p.mpb3[t2 * 16 + c];

    bf16x8 Bw2[2][4], Bw3[2][2];
    #pragma unroll
    for (int f = 0; f < 2; ++f)
        #pragma unroll
        for (int t4 = 0; t4 < 4; ++t4) {
            const float* src = p.mpW2 + (t4 * 16 + c) * 64 + f * 32 + q * 8;
            bf16x8 v;
            #pragma unroll
            for (int s = 0; s < 8; ++s) v[s] = (__bf16)src[s];
            Bw2[f][t4] = v;
        }
    #pragma unroll
    for (int f = 0; f < 2; ++f)
        #pragma unroll
        for (int t2 = 0; t2 < 2; ++t2) {
            const float* src = p.mpW3 + (t2 * 16 + c) * 64 + f * 32 + q * 8;
            bf16x8 v;
            #pragma unroll
            for (int s = 0; s < 8; ++s) v[s] = (__bf16)src[s];
            Bw3[f][t2] = v;
        }

    // J column j (direct strided gather, once; J is read-only input)
    const float jA = p.J[(nw * 128 + lane) * NN + j];
    const float jB = p.J[(nw * 128 + 64 + lane) * NN + j];

    const floatx4 zero4 = {0.f, 0.f, 0.f, 0.f};

    xbarrier(p.bar, 1);    // hip0 visible everywhere

    // ---------------- 5 message-passing steps ----------------
    for (int t = 0; t < 5; ++t) {
        const float* hb_read = (t & 1) ? p.hb1 : p.hb0;
        float*       hb_next = (t & 1) ? p.hb0 : p.hb1;

        float hjp_r[16];
        #pragma unroll
        for (int s = 0; s < 8; ++s) {
            hjp_r[s]     = hjpS[nsel][q * 8 + s];
            hjp_r[8 + s] = hjpS[nsel][q * 8 + s + 32];
        }
        float accf[2][4];
        #pragma unroll
        for (int t2 = 0; t2 < 2; ++t2)
            #pragma unroll
            for (int r = 0; r < 4; ++r) accf[t2][r] = 0.0f;

        // ---- edge phase: pipelined bypass loads (vmcnt fully ours) ----
        floatx4 pf[2][4];
        issue4(hb_read + (nw * 128 + c) * 64 + q * 8,
               pf[0][0], pf[0][1], pf[0][2], pf[0][3]);

        #pragma unroll
        for (int g = 0; g < 8; ++g) {
            if (g < 7) {
                issue4(hb_read + (nw * 128 + (g + 1) * 16 + c) * 64 + q * 8,
                       pf[(g + 1) & 1][0], pf[(g + 1) & 1][1],
                       pf[(g + 1) & 1][2], pf[(g + 1) & 1][3]);
                wait4_4(pf[g & 1][0], pf[g & 1][1], pf[g & 1][2], pf[g & 1][3]);
            } else {
                wait4_0(pf[g & 1][0], pf[g & 1][1], pf[g & 1][2], pf[g & 1][3]);
            }
            floatx4 h0 = pf[g & 1][0], h1 = pf[g & 1][1];
            floatx4 h2 = pf[g & 1][2], h3 = pf[g & 1][3];

            float Jv = __shfl((g < 4) ? jA : jB, (g & 3) * 16 + c);

            float va[16];
            va[0]  = h0[0]; va[1]  = h0[1]; va[2]  = h0[2]; va[3]  = h0[3];
            va[4]  = h1[0]; va[5]  = h1[1]; va[6]  = h1[2]; va[7]  = h1[3];
            va[8]  = h2[0]; va[9]  = h2[1]; va[10] = h2[2]; va[11] = h2[3];
            va[12] = h3[0]; va[13] = h3[1]; va[14] = h3[2]; va[15] = h3[3];

            bf16x8 a0, a1;
            #pragma unroll
            for (int s = 0; s < 8; ++s) {
                float v0 = fmaf(Jv, wj_r[s],     va[s]     + hjp_r[s]);
                float v1 = fmaf(Jv, wj_r[8 + s], va[8 + s] + hjp_r[8 + s]);
                a0[s] = (__bf16)fmaxf(v0, 0.0f);
                a1[s] = (__bf16)fmaxf(v1, 0.0f);
            }

            floatx4 c1[4];
            #pragma unroll
            for (int t4 = 0; t4 < 4; ++t4) {
                c1[t4] = __builtin_amdgcn_mfma_f32_16x16x32_bf16(a0, Bw2[0][t4], zero4, 0, 0, 0);
                c1[t4] = __builtin_amdgcn_mfma_f32_16x16x32_bf16(a1, Bw2[1][t4], c1[t4], 0, 0, 0);
            }

            #pragma unroll
            for (int t4 = 0; t4 < 4; ++t4)
                #pragma unroll
                for (int r = 0; r < 4; ++r)
                    m2f[wave][q * 4 + r][t4 * 16 + c] = fmaxf(c1[t4][r] + b2v[t4], 0.0f);

            asm volatile("s_waitcnt lgkmcnt(0)" ::: "memory");  // same-wave RAW

            float4 ra0 = *(const float4*)&m2f[wave][c][q * 8];
            float4 ra1 = *(const float4*)&m2f[wave][c][q * 8 + 4];
            float4 ra2 = *(const float4*)&m2f[wave][c][q * 8 + 32];
            float4 ra3 = *(const float4*)&m2f[wave][c][q * 8 + 36];

            bf16x8 a2, a3;
            a2[0] = (__bf16)ra0.x; a2[1] = (__bf16)ra0.y; a2[2] = (__bf16)ra0.z; a2[3] = (__bf16)ra0.w;
            a2[4] = (__bf16)ra1.x; a2[5] = (__bf16)ra1.y; a2[6] = (__bf16)ra1.z; a2[7] = (__bf16)ra1.w;
            a3[0] = (__bf16)ra2.x; a3[1] = (__bf16)ra2.y; a3[2] = (__bf16)ra2.z; a3[3] = (__bf16)ra2.w;
            a3[4] = (__bf16)ra3.x; a3[5] = (__bf16)ra3.y; a3[6] = (__bf16)ra3.z; a3[7] = (__bf16)ra3.w;

            floatx4 c2[2];
            #pragma unroll
            for (int t2 = 0; t2 < 2; ++t2) {
                c2[t2] = __builtin_amdgcn_mfma_f32_16x16x32_bf16(a2, Bw3[0][t2], zero4, 0, 0, 0);
                c2[t2] = __builtin_amdgcn_mfma_f32_16x16x32_bf16(a3, Bw3[1][t2], c2[t2], 0, 0, 0);
            }
            #pragma unroll
            for (int t2 = 0; t2 < 2; ++t2)
                #pragma unroll
                for (int r = 0; r < 4; ++r)
                    accf[t2][r] += fmaxf(c2[t2][r] + b3v[t2], 0.0f);

            asm volatile("s_waitcnt lgkmcnt(0)" ::: "memory");  // WAR
        }

        // column sums
        float s0 = accf[0][0] + accf[0][1] + accf[0][2] + accf[0][3];
        float s1 = accf[1][0] + accf[1][1] + accf[1][2] + accf[1][3];
        s0 += __shfl_xor(s0, 16); s0 += __shfl_xor(s0, 32);
        s1 += __shfl_xor(s1, 16); s1 += __shfl_xor(s1, 32);
        if (lane < 16) {
            msum[wave][c]      = s0;
            msum[wave][16 + c] = s1;
        }
        __syncthreads();

        // ---- block-local tail ----
        if (tid < 64) {
            int node = tid >> 5, d = tid & 31;
            msgS[node][d] = msum[node * 4 + 0][d] + msum[node * 4 + 1][d] +
                            msum[node * 4 + 2][d] + msum[node * 4 + 3][d];
        }
        __syncthreads();

        if (tid < 192) {
            int node = tid / 96, r = tid % 96;
            int g = r >> 5, d = r & 31;
            const float* wi = p.Wih + (g * 32 + d) * 64;
            float a  = p.bih[g * 32 + d];
            float bb = p.bhh[g * 32 + d];
            if (t > 0) {
                const float* wh = p.Whh + (g * 32 + d) * 32;
                #pragma unroll
                for (int k = 0; k < 32; ++k) {
                    float hv = hS[node][k];
                    a  = fmaf(hv, wi[k], a);
                    bb = fmaf(hv, wh[k], bb);
                }
            }
            #pragma unroll
            for (int k = 0; k < 32; ++k) a = fmaf(msgS[node][k], wi[32 + k], a);
            giS[node][r] = a; ghS[node][r] = bb;
        }
        __syncthreads();

        if (tid < 64) {
            int node = tid >> 5, d = tid & 31;
            float r  = sigmoidf_(giS[node][d] + ghS[node][d]);
            float z  = sigmoidf_(giS[node][32 + d] + ghS[node][32 + d]);
            float ng = tanhf(giS[node][64 + d] + r * ghS[node][64 + d]);
            float hold = (t > 0) ? hS[node][d] : 0.0f;
            hS[node][d] = (1.0f - z) * ng + z * hold;
        }
        __syncthreads();

        if (t < 4) {
            if (tid < 128) {   // projections for next step -> hjpS + LLC
                int node = tid >> 6, cc = tid & 63;
                int jj = blockIdx.x * 2 + node;
                const float* wr = p.mpW1 + cc * 67;
                float bj = p.b[jj];
                float si = bj * wr[65];
                float sj = bj * wr[66] + p.mpb1[cc];
                #pragma unroll
                for (int d = 0; d < 32; ++d) {
                    float hv = hS[node][d];
                    si = fmaf(hv, wr[d], si);
                    sj = fmaf(hv, wr[32 + d], sj);
                }
                hjpS[node][cc] = sj;
                atomicExch(&hb_next[jj * HM + cc], si);
            }
            xbarrier(p.bar, (unsigned)(t + 2));
        } else {
            if (wave < 2) {   // readout
                int node = wave;
                int jj = blockIdx.x * 2 + node;
                float y1 = p.rb1[lane];
                #pragma unroll
                for (int k = 0; k < 32; ++k) y1 = fmaf(hS[node][k], p.rW1[lane * 32 + k], y1);
                y1 = fmaxf(y1, 0.0f);
                float y2 = p.rb2[lane];
                #pragma unroll
                for (int k = 0; k < 64; ++k) y2 = fmaf(__shfl(y1, k), p.rW2[lane * 64 + k], y2);
                y2 = fmaxf(y2, 0.0f);
                float y3 = (lane < 2) ? p.rb3[lane] : 0.0f;
                #pragma unroll
                for (int k = 0; k < 64; ++k) {
                    float v = __shfl(y2, k);
                    if (lane < 2) y3 = fmaf(v, p.rW3[lane * 64 + k], y3);
                }
                if (lane < 2) p.out[jj * 2 + lane] = sigmoidf_(y3);
            }
        }
    }
}

// ---------------------------------------------------------------------------
extern "C" void kernel_launch(void* const* d_in, const int* in_sizes, int n_in,
                              void* d_out, int out_size, void* d_ws, size_t ws_size,
                              hipStream_t stream)
{
    float* ws = (float*)d_ws;

    KParams p;
    p.J    = (const float*)d_in[0];
    p.b    = (const float*)d_in[1];
    p.mpW1 = (const float*)d_in[2];
    p.mpb1 = (const float*)d_in[3];
    p.mpW2 = (const float*)d_in[4];
    p.mpb2 = (const float*)d_in[5];
    p.mpW3 = (const float*)d_in[6];
    p.mpb3 = (const float*)d_in[7];
    p.Wih  = (const float*)d_in[8];
    p.Whh  = (const float*)d_in[9];
    p.bih  = (const float*)d_in[10];
    p.bhh  = (const float*)d_in[11];
    p.rW1  = (const float*)d_in[12];
    p.rb1  = (const float*)d_in[13];
    p.rW2  = (const float*)d_in[14];
    p.rb2  = (const float*)d_in[15];
    p.rW3  = (const float*)d_in[16];
    p.rb3  = (const float*)d_in[17];
    p.out  = (float*)d_out;

    p.hb0  = ws;                       // 512*64 f32
    p.hb1  = ws + 32768;               // 512*64 f32
    p.bar  = (unsigned*)(ws + 65536);  // 2 u32

    hipMemsetAsync(p.bar, 0, 8, stream);   // zero barrier state each launch

    void* kargs[] = { &p };
    hipLaunchCooperativeKernel((const void*)fused_kernel, dim3(NB), dim3(512),
                               kargs, 0, stream);
}

// Round 6
// 182.990 us; speedup vs baseline: 2.9083x; 1.2064x over previous
//
#include <hip/hip_runtime.h>
#include <math.h>

#define NN 512     // N_NODES
#define SD 32      // STATE_DIM == MESSAGE_DIM
#define HM 64      // H_MSG
#define NB 256     // blocks
#define NGRP 16    // barrier tree groups (16 blocks each)

typedef __bf16 bf16x8 __attribute__((ext_vector_type(8)));
typedef float floatx4 __attribute__((ext_vector_type(4)));

struct KParams {
    const float *J, *b, *mpW1, *mpb1, *mpW2, *mpb2, *mpW3, *mpb3;
    const float *Wih, *Whh, *bih, *bhh;
    const float *rW1, *rb1, *rW2, *rb2, *rW3, *rb3;
    float *out;
    float *hb0, *hb1;   // hip double buffers (512x64 f32), exchanged at LLC
    unsigned *bar;      // [g*16] group counters g=0..15, [256] root, [272] gen
};

__device__ __forceinline__ float sigmoidf_(float x) {
    return 1.0f / (1.0f + __expf(-x));
}

// ---- coherence-point primitives (no L2 cache maintenance anywhere) --------
__device__ __forceinline__ unsigned ld_bypass_u32(const unsigned* p) {
    unsigned r;
    asm volatile("global_load_dword %0, %1, off sc0 sc1\n\ts_waitcnt vmcnt(0)"
                 : "=v"(r) : "v"(p) : "memory");
    return r;
}
// issue 4x16B bypass loads (one group's A-operand rows), no wait
__device__ __forceinline__ void issue4(const float* base,
        floatx4& a, floatx4& b, floatx4& c, floatx4& d) {
    asm volatile(
        "global_load_dwordx4 %0, %4, off sc0 sc1\n\t"
        "global_load_dwordx4 %1, %4, off offset:16 sc0 sc1\n\t"
        "global_load_dwordx4 %2, %4, off offset:128 sc0 sc1\n\t"
        "global_load_dwordx4 %3, %4, off offset:144 sc0 sc1"
        : "=&v"(a), "=&v"(b), "=&v"(c), "=&v"(d) : "v"(base));
}
__device__ __forceinline__ void wait4_8(floatx4& a, floatx4& b, floatx4& c, floatx4& d) {
    asm volatile("s_waitcnt vmcnt(8)" : "+v"(a), "+v"(b), "+v"(c), "+v"(d));
}
__device__ __forceinline__ void wait4_4(floatx4& a, floatx4& b, floatx4& c, floatx4& d) {
    asm volatile("s_waitcnt vmcnt(4)" : "+v"(a), "+v"(b), "+v"(c), "+v"(d));
}
__device__ __forceinline__ void wait4_0(floatx4& a, floatx4& b, floatx4& c, floatx4& d) {
    asm volatile("s_waitcnt vmcnt(0)" : "+v"(a), "+v"(b), "+v"(c), "+v"(d));
}

// Tree sense barrier (monotonic rounds, 1-based). Arrival: atomicAdd on
// per-group counter (own cacheline) -> group leader adds to root -> last
// leader publishes gen. Spin via sc0sc1 bypass loads + s_sleep.
// No cache maintenance ops anywhere.
__device__ __forceinline__ void xbarrier(unsigned* bar, unsigned round, int bid) {
    __syncthreads();   // drains each wave's vmem (incl. atomicExch h-stores)
    if (threadIdx.x == 0) {
        unsigned g = (unsigned)bid >> 4;   // 16 blocks per group
        unsigned old = atomicAdd(&bar[g * 16], 1u);
        if (old + 1u == round * NGRP) {
            unsigned r2 = atomicAdd(&bar[256], 1u);
            if (r2 + 1u == round * NGRP) {
                atomicMax(&bar[272], round);
            } else {
                while (ld_bypass_u32(&bar[272]) < round) __builtin_amdgcn_s_sleep(2);
            }
        } else {
            while (ld_bypass_u32(&bar[272]) < round) __builtin_amdgcn_s_sleep(2);
        }
    }
    __syncthreads();
}

// One kernel, 256 blocks x 512 threads; block owns nodes j0=2*bid, j1=2*bid+1
// (waves 0-3 / 4-7). Cross-block data = hip[] only: producers atomicExch
// (coherence point), consumers sc0sc1 bypass loads, tree barrier between
// steps. h/hjp block-local in LDS. 256 blocks @ <=1 block/CU resources =>
// all co-resident (capacity 2/CU), spin barrier safe without coop launch.
__global__ __launch_bounds__(512, 2) void fused_kernel(KParams p)
{
    __shared__ __align__(16) float m2f[8][16][68];
    __shared__ float msum[8][32];
    __shared__ float hjpS[2][64];
    __shared__ float hS[2][32];
    __shared__ float msgS[2][32];
    __shared__ float giS[2][96], ghS[2][96];

    const int tid  = threadIdx.x;
    const int lane = tid & 63;
    const int wave = tid >> 6;       // 0..7
    const int nsel = wave >> 2;      // node select
    const int nw   = wave & 3;       // wave-within-node
    const int j    = blockIdx.x * 2 + nsel;
    const int q    = lane >> 4;
    const int c    = lane & 15;

    // ---------------- prep: h==0 projections for own nodes ----------------
    if (tid < 128) {
        int node = tid >> 6, cc = tid & 63;
        int jj = blockIdx.x * 2 + node;
        const float* wr = p.mpW1 + cc * 67;
        float bj = p.b[jj];
        hjpS[node][cc] = bj * wr[66] + p.mpb1[cc];
        atomicExch(&p.hb0[jj * HM + cc], bj * wr[65]);   // hip0 -> LLC
    }

    // ---------------- persistent per-lane preloads ----------------
    float wj_r[16], b2v[4], b3v[2];
    #pragma unroll
    for (int s = 0; s < 8; ++s) {
        wj_r[s]     = p.mpW1[(q * 8 + s) * 67 + 64];
        wj_r[8 + s] = p.mpW1[(q * 8 + s + 32) * 67 + 64];
    }
    #pragma unroll
    for (int t4 = 0; t4 < 4; ++t4) b2v[t4] = p.mpb2[t4 * 16 + c];
    #pragma unroll
    for (int t2 = 0; t2 < 2; ++t2) b3v[t2] = p.mpb3[t2 * 16 + c];

    bf16x8 Bw2[2][4], Bw3[2][2];
    #pragma unroll
    for (int f = 0; f < 2; ++f)
        #pragma unroll
        for (int t4 = 0; t4 < 4; ++t4) {
            const float* src = p.mpW2 + (t4 * 16 + c) * 64 + f * 32 + q * 8;
            bf16x8 v;
            #pragma unroll
            for (int s = 0; s < 8; ++s) v[s] = (__bf16)src[s];
            Bw2[f][t4] = v;
        }
    #pragma unroll
    for (int f = 0; f < 2; ++f)
        #pragma unroll
        for (int t2 = 0; t2 < 2; ++t2) {
            const float* src = p.mpW3 + (t2 * 16 + c) * 64 + f * 32 + q * 8;
            bf16x8 v;
            #pragma unroll
            for (int s = 0; s < 8; ++s) v[s] = (__bf16)src[s];
            Bw3[f][t2] = v;
        }

    // J column j (direct strided gather, once; J is read-only input)
    const float jA = p.J[(nw * 128 + lane) * NN + j];
    const float jB = p.J[(nw * 128 + 64 + lane) * NN + j];

    const floatx4 zero4 = {0.f, 0.f, 0.f, 0.f};

    xbarrier(p.bar, 1, blockIdx.x);    // hip0 visible everywhere

    // ---------------- 5 message-passing steps ----------------
    for (int t = 0; t < 5; ++t) {
        const float* hb_read = (t & 1) ? p.hb1 : p.hb0;
        float*       hb_next = (t & 1) ? p.hb0 : p.hb1;

        float hjp_r[16];
        #pragma unroll
        for (int s = 0; s < 8; ++s) {
            hjp_r[s]     = hjpS[nsel][q * 8 + s];
            hjp_r[8 + s] = hjpS[nsel][q * 8 + s + 32];
        }
        float accf[2][4];
        #pragma unroll
        for (int t2 = 0; t2 < 2; ++t2)
            #pragma unroll
            for (int r = 0; r < 4; ++r) accf[t2][r] = 0.0f;

        // ---- edge phase: depth-2 pipelined bypass loads ----
        floatx4 pf[3][4];
        issue4(hb_read + (nw * 128 + 0 * 16 + c) * 64 + q * 8,
               pf[0][0], pf[0][1], pf[0][2], pf[0][3]);
        issue4(hb_read + (nw * 128 + 1 * 16 + c) * 64 + q * 8,
               pf[1][0], pf[1][1], pf[1][2], pf[1][3]);

        #pragma unroll
        for (int g = 0; g < 8; ++g) {
            const int cur = g % 3;
            if (g < 6) {
                const int nxt = (g + 2) % 3;
                issue4(hb_read + (nw * 128 + (g + 2) * 16 + c) * 64 + q * 8,
                       pf[nxt][0], pf[nxt][1], pf[nxt][2], pf[nxt][3]);
                wait4_8(pf[cur][0], pf[cur][1], pf[cur][2], pf[cur][3]);
            } else if (g == 6) {
                wait4_4(pf[cur][0], pf[cur][1], pf[cur][2], pf[cur][3]);
            } else {
                wait4_0(pf[cur][0], pf[cur][1], pf[cur][2], pf[cur][3]);
            }
            floatx4 h0 = pf[cur][0], h1 = pf[cur][1];
            floatx4 h2 = pf[cur][2], h3 = pf[cur][3];

            float Jv = __shfl((g < 4) ? jA : jB, (g & 3) * 16 + c);

            float va[16];
            va[0]  = h0[0]; va[1]  = h0[1]; va[2]  = h0[2]; va[3]  = h0[3];
            va[4]  = h1[0]; va[5]  = h1[1]; va[6]  = h1[2]; va[7]  = h1[3];
            va[8]  = h2[0]; va[9]  = h2[1]; va[10] = h2[2]; va[11] = h2[3];
            va[12] = h3[0]; va[13] = h3[1]; va[14] = h3[2]; va[15] = h3[3];

            bf16x8 a0, a1;
            #pragma unroll
            for (int s = 0; s < 8; ++s) {
                float v0 = fmaf(Jv, wj_r[s],     va[s]     + hjp_r[s]);
                float v1 = fmaf(Jv, wj_r[8 + s], va[8 + s] + hjp_r[8 + s]);
                a0[s] = (__bf16)fmaxf(v0, 0.0f);
                a1[s] = (__bf16)fmaxf(v1, 0.0f);
            }

            floatx4 c1[4];
            #pragma unroll
            for (int t4 = 0; t4 < 4; ++t4) {
                c1[t4] = __builtin_amdgcn_mfma_f32_16x16x32_bf16(a0, Bw2[0][t4], zero4, 0, 0, 0);
                c1[t4] = __builtin_amdgcn_mfma_f32_16x16x32_bf16(a1, Bw2[1][t4], c1[t4], 0, 0, 0);
            }

            #pragma unroll
            for (int t4 = 0; t4 < 4; ++t4)
                #pragma unroll
                for (int r = 0; r < 4; ++r)
                    m2f[wave][q * 4 + r][t4 * 16 + c] = fmaxf(c1[t4][r] + b2v[t4], 0.0f);

            asm volatile("s_waitcnt lgkmcnt(0)" ::: "memory");  // same-wave RAW

            float4 ra0 = *(const float4*)&m2f[wave][c][q * 8];
            float4 ra1 = *(const float4*)&m2f[wave][c][q * 8 + 4];
            float4 ra2 = *(const float4*)&m2f[wave][c][q * 8 + 32];
            float4 ra3 = *(const float4*)&m2f[wave][c][q * 8 + 36];

            bf16x8 a2, a3;
            a2[0] = (__bf16)ra0.x; a2[1] = (__bf16)ra0.y; a2[2] = (__bf16)ra0.z; a2[3] = (__bf16)ra0.w;
            a2[4] = (__bf16)ra1.x; a2[5] = (__bf16)ra1.y; a2[6] = (__bf16)ra1.z; a2[7] = (__bf16)ra1.w;
            a3[0] = (__bf16)ra2.x; a3[1] = (__bf16)ra2.y; a3[2] = (__bf16)ra2.z; a3[3] = (__bf16)ra2.w;
            a3[4] = (__bf16)ra3.x; a3[5] = (__bf16)ra3.y; a3[6] = (__bf16)ra3.z; a3[7] = (__bf16)ra3.w;

            floatx4 c2[2];
            #pragma unroll
            for (int t2 = 0; t2 < 2; ++t2) {
                c2[t2] = __builtin_amdgcn_mfma_f32_16x16x32_bf16(a2, Bw3[0][t2], zero4, 0, 0, 0);
                c2[t2] = __builtin_amdgcn_mfma_f32_16x16x32_bf16(a3, Bw3[1][t2], c2[t2], 0, 0, 0);
            }
            #pragma unroll
            for (int t2 = 0; t2 < 2; ++t2)
                #pragma unroll
                for (int r = 0; r < 4; ++r)
                    accf[t2][r] += fmaxf(c2[t2][r] + b3v[t2], 0.0f);

            asm volatile("s_waitcnt lgkmcnt(0)" ::: "memory");  // WAR
        }

        // column sums
        float s0 = accf[0][0] + accf[0][1] + accf[0][2] + accf[0][3];
        float s1 = accf[1][0] + accf[1][1] + accf[1][2] + accf[1][3];
        s0 += __shfl_xor(s0, 16); s0 += __shfl_xor(s0, 32);
        s1 += __shfl_xor(s1, 16); s1 += __shfl_xor(s1, 32);
        if (lane < 16) {
            msum[wave][c]      = s0;
            msum[wave][16 + c] = s1;
        }
        __syncthreads();

        // ---- block-local tail ----
        if (tid < 64) {
            int node = tid >> 5, d = tid & 31;
            msgS[node][d] = msum[node * 4 + 0][d] + msum[node * 4 + 1][d] +
                            msum[node * 4 + 2][d] + msum[node * 4 + 3][d];
        }
        __syncthreads();

        if (tid < 192) {
            int node = tid / 96, r = tid % 96;
            int g = r >> 5, d = r & 31;
            const float* wi = p.Wih + (g * 32 + d) * 64;
            float a  = p.bih[g * 32 + d];
            float bb = p.bhh[g * 32 + d];
            if (t > 0) {
                const float* wh = p.Whh + (g * 32 + d) * 32;
                #pragma unroll
                for (int k = 0; k < 32; ++k) {
                    float hv = hS[node][k];
                    a  = fmaf(hv, wi[k], a);
                    bb = fmaf(hv, wh[k], bb);
                }
            }
            #pragma unroll
            for (int k = 0; k < 32; ++k) a = fmaf(msgS[node][k], wi[32 + k], a);
            giS[node][r] = a; ghS[node][r] = bb;
        }
        __syncthreads();

        if (tid < 64) {
            int node = tid >> 5, d = tid & 31;
            float r  = sigmoidf_(giS[node][d] + ghS[node][d]);
            float z  = sigmoidf_(giS[node][32 + d] + ghS[node][32 + d]);
            float ng = tanhf(giS[node][64 + d] + r * ghS[node][64 + d]);
            float hold = (t > 0) ? hS[node][d] : 0.0f;
            hS[node][d] = (1.0f - z) * ng + z * hold;
        }
        __syncthreads();

        if (t < 4) {
            if (tid < 128) {   // projections for next step -> hjpS + LLC
                int node = tid >> 6, cc = tid & 63;
                int jj = blockIdx.x * 2 + node;
                const float* wr = p.mpW1 + cc * 67;
                float bj = p.b[jj];
                float si = bj * wr[65];
                float sj = bj * wr[66] + p.mpb1[cc];
                #pragma unroll
                for (int d = 0; d < 32; ++d) {
                    float hv = hS[node][d];
                    si = fmaf(hv, wr[d], si);
                    sj = fmaf(hv, wr[32 + d], sj);
                }
                hjpS[node][cc] = sj;
                atomicExch(&hb_next[jj * HM + cc], si);
            }
            xbarrier(p.bar, (unsigned)(t + 2), blockIdx.x);
        } else {
            if (wave < 2) {   // readout
                int node = wave;
                int jj = blockIdx.x * 2 + node;
                float y1 = p.rb1[lane];
                #pragma unroll
                for (int k = 0; k < 32; ++k) y1 = fmaf(hS[node][k], p.rW1[lane * 32 + k], y1);
                y1 = fmaxf(y1, 0.0f);
                float y2 = p.rb2[lane];
                #pragma unroll
                for (int k = 0; k < 64; ++k) y2 = fmaf(__shfl(y1, k), p.rW2[lane * 64 + k], y2);
                y2 = fmaxf(y2, 0.0f);
                float y3 = (lane < 2) ? p.rb3[lane] : 0.0f;
                #pragma unroll
                for (int k = 0; k < 64; ++k) {
                    float v = __shfl(y2, k);
                    if (lane < 2) y3 = fmaf(v, p.rW3[lane * 64 + k], y3);
                }
                if (lane < 2) p.out[jj * 2 + lane] = sigmoidf_(y3);
            }
        }
    }
}

// ---------------------------------------------------------------------------
extern "C" void kernel_launch(void* const* d_in, const int* in_sizes, int n_in,
                              void* d_out, int out_size, void* d_ws, size_t ws_size,
                              hipStream_t stream)
{
    float* ws = (float*)d_ws;

    KParams p;
    p.J    = (const float*)d_in[0];
    p.b    = (const float*)d_in[1];
    p.mpW1 = (const float*)d_in[2];
    p.mpb1 = (const float*)d_in[3];
    p.mpW2 = (const float*)d_in[4];
    p.mpb2 = (const float*)d_in[5];
    p.mpW3 = (const float*)d_in[6];
    p.mpb3 = (const float*)d_in[7];
    p.Wih  = (const float*)d_in[8];
    p.Whh  = (const float*)d_in[9];
    p.bih  = (const float*)d_in[10];
    p.bhh  = (const float*)d_in[11];
    p.rW1  = (const float*)d_in[12];
    p.rb1  = (const float*)d_in[13];
    p.rW2  = (const float*)d_in[14];
    p.rb2  = (const float*)d_in[15];
    p.rW3  = (const float*)d_in[16];
    p.rb3  = (const float*)d_in[17];
    p.out  = (float*)d_out;

    p.hb0  = ws;                       // 512*64 f32
    p.hb1  = ws + 32768;               // 512*64 f32
    p.bar  = (unsigned*)(ws + 65536);  // tree barrier state (<=4KB)

    hipMemsetAsync(p.bar, 0, 4096, stream);   // zero barrier state each launch

    fused_kernel<<<dim3(NB), dim3(512), 0, stream>>>(p);
}

// Round 7
// 177.550 us; speedup vs baseline: 2.9974x; 1.0306x over previous
//
#include <hip/hip_runtime.h>
#include <math.h>

#define NN 512     // N_NODES
#define SD 32      // STATE_DIM == MESSAGE_DIM
#define HM 64      // H_MSG
#define NB 256     // blocks
#define NGRP 16    // barrier tree groups

typedef __bf16 bf16x8 __attribute__((ext_vector_type(8)));
typedef float floatx4 __attribute__((ext_vector_type(4)));
typedef unsigned uintx4 __attribute__((ext_vector_type(4)));

// ---- dynamic LDS layout (bytes) ----
#define OFF_M2F   0          // float [8][16][68]      = 34816
#define OFF_HBS   34816      // 512 rows x 152 B (bf16)= 77824
#define OFF_WIH   112640     // float 96x65            = 24960
#define OFF_WHH   137600     // float 96x33            = 12672
#define OFF_BIH   150272     // 96 f
#define OFF_BHH   150656     // 96 f
#define OFF_MSUM  151040     // 8x32 f                 = 1024
#define OFF_HJP   152064     // 2x64 f
#define OFF_H     152576     // 2x32 f
#define OFF_MSG   152832     // 2x32 f
#define OFF_GI    153088     // 2x96 f
#define OFF_GH    153856     // 2x96 f
#define LDS_TOTAL 154624

struct KParams {
    const float *J, *b, *mpW1, *mpb1, *mpW2, *mpb2, *mpW3, *mpb3;
    const float *Wih, *Whh, *bih, *bhh;
    const float *rW1, *rb1, *rW2, *rb2, *rW3, *rb3;
    float *out;
    unsigned *hb0, *hb1;   // hip double buffers, PACKED bf16 pairs (512*32 u32)
    unsigned *bar;         // tree barrier state
};

__device__ __forceinline__ float sigmoidf_(float x) {
    return 1.0f / (1.0f + __expf(-x));
}

// ---- coherence-point primitives (no cache maintenance anywhere) -----------
__device__ __forceinline__ unsigned ld_bypass_u32(const unsigned* p) {
    unsigned r;
    asm volatile("global_load_dword %0, %1, off sc0 sc1\n\ts_waitcnt vmcnt(0)"
                 : "=v"(r) : "v"(p) : "memory");
    return r;
}
__device__ __forceinline__ void issue1(const unsigned* p, uintx4& d) {
    asm volatile("global_load_dwordx4 %0, %1, off sc0 sc1"
                 : "=v"(d) : "v"(p));
}
__device__ __forceinline__ void waitall8(uintx4* c) {
    asm volatile("s_waitcnt vmcnt(0)"
                 : "+v"(c[0]), "+v"(c[1]), "+v"(c[2]), "+v"(c[3]),
                   "+v"(c[4]), "+v"(c[5]), "+v"(c[6]), "+v"(c[7]) :: "memory");
}
__device__ __forceinline__ void unpk(unsigned u, float& lo, float& hi) {
    lo = __uint_as_float(u << 16);
    hi = __uint_as_float(u & 0xffff0000u);
}

// Tree sense barrier (monotonic rounds, 1-based).
__device__ __forceinline__ void xbarrier(unsigned* bar, unsigned round, int bid) {
    __syncthreads();   // drains each wave's vmem (incl. atomicExch h-stores)
    if (threadIdx.x == 0) {
        unsigned g = (unsigned)bid >> 4;
        unsigned old = atomicAdd(&bar[g * 16], 1u);
        if (old + 1u == round * NGRP) {
            unsigned r2 = atomicAdd(&bar[256], 1u);
            if (r2 + 1u == round * NGRP) {
                atomicMax(&bar[272], round);
            } else {
                while (ld_bypass_u32(&bar[272]) < round) __builtin_amdgcn_s_sleep(2);
            }
        } else {
            while (ld_bypass_u32(&bar[272]) < round) __builtin_amdgcn_s_sleep(2);
        }
    }
    __syncthreads();
}

// 256 blocks x 512 threads; block owns nodes 2*bid, 2*bid+1 (waves 0-3/4-7).
// Cross-block data: packed-bf16 hip via atomicExch (LLC) -> per-block LDS
// staging with sc0sc1 bypass loads (16 MB/step total, 4x less than R6).
// GRU weights in LDS. 1 block/CU, all 256 co-resident -> spin barrier safe.
__global__ __launch_bounds__(512, 1) void fused_kernel(KParams p)
{
    extern __shared__ __align__(16) char smem[];
    float (*m2f)[16][68] = (float(*)[16][68])(smem + OFF_M2F);
    char*  hbS  = smem + OFF_HBS;                 // bf16 rows, stride 152 B
    float* WihS = (float*)(smem + OFF_WIH);       // stride 65
    float* WhhS = (float*)(smem + OFF_WHH);       // stride 33
    float* biS  = (float*)(smem + OFF_BIH);
    float* bhS  = (float*)(smem + OFF_BHH);
    float (*msum)[32] = (float(*)[32])(smem + OFF_MSUM);
    float (*hjpS)[64] = (float(*)[64])(smem + OFF_HJP);
    float (*hS)[32]   = (float(*)[32])(smem + OFF_H);
    float (*msgS)[32] = (float(*)[32])(smem + OFF_MSG);
    float (*giS)[96]  = (float(*)[96])(smem + OFF_GI);
    float (*ghS)[96]  = (float(*)[96])(smem + OFF_GH);

    const int tid  = threadIdx.x;
    const int lane = tid & 63;
    const int wave = tid >> 6;       // 0..7
    const int nsel = wave >> 2;      // node select
    const int nw   = wave & 3;       // wave-within-node
    const int j    = blockIdx.x * 2 + nsel;
    const int q    = lane >> 4;
    const int c    = lane & 15;

    // ---------------- prep: weights -> LDS ----------------
    for (int n = tid; n < 96 * 64; n += 512)
        WihS[(n >> 6) * 65 + (n & 63)] = p.Wih[n];
    for (int n = tid; n < 96 * 32; n += 512)
        WhhS[(n >> 5) * 33 + (n & 31)] = p.Whh[n];
    if (tid < 96) biS[tid] = p.bih[tid];
    else if (tid < 192) bhS[tid - 96] = p.bhh[tid - 96];

    // ---------------- prep: h==0 projections, packed bf16 -> LLC ----------
    if (tid < 128) {
        int node = tid >> 6, cc = tid & 63;
        int jj = blockIdx.x * 2 + node;
        const float* wr = p.mpW1 + cc * 67;
        float bj = p.b[jj];
        hjpS[node][cc] = bj * wr[66] + p.mpb1[cc];
        float si = bj * wr[65];
        float sp = __shfl(si, lane ^ 1);
        if (!(lane & 1)) {
            unsigned pk = (unsigned)__builtin_bit_cast(unsigned short, (__bf16)si)
                        | ((unsigned)__builtin_bit_cast(unsigned short, (__bf16)sp) << 16);
            atomicExch(&p.hb0[jj * 32 + (cc >> 1)], pk);
        }
    }

    // ---------------- persistent per-lane preloads ----------------
    float wj_r[16], b2v[4], b3v[2];
    #pragma unroll
    for (int s = 0; s < 8; ++s) {
        wj_r[s]     = p.mpW1[(q * 8 + s) * 67 + 64];
        wj_r[8 + s] = p.mpW1[(q * 8 + s + 32) * 67 + 64];
    }
    #pragma unroll
    for (int t4 = 0; t4 < 4; ++t4) b2v[t4] = p.mpb2[t4 * 16 + c];
    #pragma unroll
    for (int t2 = 0; t2 < 2; ++t2) b3v[t2] = p.mpb3[t2 * 16 + c];

    bf16x8 Bw2[2][4], Bw3[2][2];
    #pragma unroll
    for (int f = 0; f < 2; ++f)
        #pragma unroll
        for (int t4 = 0; t4 < 4; ++t4) {
            const float* src = p.mpW2 + (t4 * 16 + c) * 64 + f * 32 + q * 8;
            bf16x8 v;
            #pragma unroll
            for (int s = 0; s < 8; ++s) v[s] = (__bf16)src[s];
            Bw2[f][t4] = v;
        }
    #pragma unroll
    for (int f = 0; f < 2; ++f)
        #pragma unroll
        for (int t2 = 0; t2 < 2; ++t2) {
            const float* src = p.mpW3 + (t2 * 16 + c) * 64 + f * 32 + q * 8;
            bf16x8 v;
            #pragma unroll
            for (int s = 0; s < 8; ++s) v[s] = (__bf16)src[s];
            Bw3[f][t2] = v;
        }

    // J column j (strided gather, once; J read-only)
    const float jA = p.J[(nw * 128 + lane) * NN + j];
    const float jB = p.J[(nw * 128 + 64 + lane) * NN + j];

    const floatx4 zero4 = {0.f, 0.f, 0.f, 0.f};

    xbarrier(p.bar, 1, blockIdx.x);    // hip0 visible everywhere

    // ---------------- 5 message-passing steps ----------------
    for (int t = 0; t < 5; ++t) {
        const unsigned* hb_read = (t & 1) ? p.hb1 : p.hb0;
        unsigned*       hb_next = (t & 1) ? p.hb0 : p.hb1;

        // ---- stage hb (packed bf16, 64 KB) -> LDS, cooperatively ----
        {
            uintx4 ck[8];
            #pragma unroll
            for (int k = 0; k < 8; ++k)
                issue1(hb_read + (k * 512 + tid) * 4, ck[k]);
            waitall8(ck);
            #pragma unroll
            for (int k = 0; k < 8; ++k) {
                int n = k * 512 + tid;
                char* dst = hbS + (n >> 3) * 152 + (n & 7) * 16;
                *(uint2*)dst       = make_uint2(ck[k][0], ck[k][1]);
                *(uint2*)(dst + 8) = make_uint2(ck[k][2], ck[k][3]);
            }
        }
        __syncthreads();

        float hjp_r[16];
        #pragma unroll
        for (int s = 0; s < 8; ++s) {
            hjp_r[s]     = hjpS[nsel][q * 8 + s];
            hjp_r[8 + s] = hjpS[nsel][q * 8 + s + 32];
        }
        float accf[2][4];
        #pragma unroll
        for (int t2 = 0; t2 < 2; ++t2)
            #pragma unroll
            for (int r = 0; r < 4; ++r) accf[t2][r] = 0.0f;

        // ---- edge phase: 8 groups of 16 rows, A-frags from LDS ----
        #pragma unroll
        for (int g = 0; g < 8; ++g) {
            const char* rb = hbS + (nw * 128 + g * 16 + c) * 152;
            uint2 u0 = *(const uint2*)(rb + q * 16);
            uint2 u1 = *(const uint2*)(rb + q * 16 + 8);
            uint2 u2 = *(const uint2*)(rb + 64 + q * 16);
            uint2 u3 = *(const uint2*)(rb + 64 + q * 16 + 8);

            float Jv = __shfl((g < 4) ? jA : jB, (g & 3) * 16 + c);

            float f[16];
            unpk(u0.x, f[0],  f[1]);  unpk(u0.y, f[2],  f[3]);
            unpk(u1.x, f[4],  f[5]);  unpk(u1.y, f[6],  f[7]);
            unpk(u2.x, f[8],  f[9]);  unpk(u2.y, f[10], f[11]);
            unpk(u3.x, f[12], f[13]); unpk(u3.y, f[14], f[15]);

            bf16x8 a0, a1;
            #pragma unroll
            for (int s = 0; s < 8; ++s) {
                float v0 = fmaf(Jv, wj_r[s],     f[s]     + hjp_r[s]);
                float v1 = fmaf(Jv, wj_r[8 + s], f[8 + s] + hjp_r[8 + s]);
                a0[s] = (__bf16)fmaxf(v0, 0.0f);
                a1[s] = (__bf16)fmaxf(v1, 0.0f);
            }

            floatx4 c1[4];
            #pragma unroll
            for (int t4 = 0; t4 < 4; ++t4) {
                c1[t4] = __builtin_amdgcn_mfma_f32_16x16x32_bf16(a0, Bw2[0][t4], zero4, 0, 0, 0);
                c1[t4] = __builtin_amdgcn_mfma_f32_16x16x32_bf16(a1, Bw2[1][t4], c1[t4], 0, 0, 0);
            }

            #pragma unroll
            for (int t4 = 0; t4 < 4; ++t4)
                #pragma unroll
                for (int r = 0; r < 4; ++r)
                    m2f[wave][q * 4 + r][t4 * 16 + c] = fmaxf(c1[t4][r] + b2v[t4], 0.0f);

            asm volatile("s_waitcnt lgkmcnt(0)" ::: "memory");  // same-wave RAW

            float4 ra0 = *(const float4*)&m2f[wave][c][q * 8];
            float4 ra1 = *(const float4*)&m2f[wave][c][q * 8 + 4];
            float4 ra2 = *(const float4*)&m2f[wave][c][q * 8 + 32];
            float4 ra3 = *(const float4*)&m2f[wave][c][q * 8 + 36];

            bf16x8 a2, a3;
            a2[0] = (__bf16)ra0.x; a2[1] = (__bf16)ra0.y; a2[2] = (__bf16)ra0.z; a2[3] = (__bf16)ra0.w;
            a2[4] = (__bf16)ra1.x; a2[5] = (__bf16)ra1.y; a2[6] = (__bf16)ra1.z; a2[7] = (__bf16)ra1.w;
            a3[0] = (__bf16)ra2.x; a3[1] = (__bf16)ra2.y; a3[2] = (__bf16)ra2.z; a3[3] = (__bf16)ra2.w;
            a3[4] = (__bf16)ra3.x; a3[5] = (__bf16)ra3.y; a3[6] = (__bf16)ra3.z; a3[7] = (__bf16)ra3.w;

            floatx4 c2[2];
            #pragma unroll
            for (int t2 = 0; t2 < 2; ++t2) {
                c2[t2] = __builtin_amdgcn_mfma_f32_16x16x32_bf16(a2, Bw3[0][t2], zero4, 0, 0, 0);
                c2[t2] = __builtin_amdgcn_mfma_f32_16x16x32_bf16(a3, Bw3[1][t2], c2[t2], 0, 0, 0);
            }
            #pragma unroll
            for (int t2 = 0; t2 < 2; ++t2)
                #pragma unroll
                for (int r = 0; r < 4; ++r)
                    accf[t2][r] += fmaxf(c2[t2][r] + b3v[t2], 0.0f);

            asm volatile("s_waitcnt lgkmcnt(0)" ::: "memory");  // WAR
        }

        // column sums
        float s0 = accf[0][0] + accf[0][1] + accf[0][2] + accf[0][3];
        float s1 = accf[1][0] + accf[1][1] + accf[1][2] + accf[1][3];
        s0 += __shfl_xor(s0, 16); s0 += __shfl_xor(s0, 32);
        s1 += __shfl_xor(s1, 16); s1 += __shfl_xor(s1, 32);
        if (lane < 16) {
            msum[wave][c]      = s0;
            msum[wave][16 + c] = s1;
        }
        __syncthreads();

        // ---- block-local tail ----
        if (tid < 64) {
            int node = tid >> 5, d = tid & 31;
            msgS[node][d] = msum[node * 4 + 0][d] + msum[node * 4 + 1][d] +
                            msum[node * 4 + 2][d] + msum[node * 4 + 3][d];
        }
        __syncthreads();

        if (tid < 192) {
            int node = tid / 96, r = tid % 96;
            int g = r >> 5, d = r & 31;
            const float* wi = WihS + (g * 32 + d) * 65;
            const float* wh = WhhS + (g * 32 + d) * 33;
            float a  = biS[g * 32 + d];
            float bb = bhS[g * 32 + d];
            if (t > 0) {
                #pragma unroll
                for (int k = 0; k < 32; ++k) {
                    float hv = hS[node][k];
                    a  = fmaf(hv, wi[k], a);
                    bb = fmaf(hv, wh[k], bb);
                }
            }
            #pragma unroll
            for (int k = 0; k < 32; ++k) a = fmaf(msgS[node][k], wi[32 + k], a);
            giS[node][r] = a; ghS[node][r] = bb;
        }
        __syncthreads();

        if (tid < 64) {
            int node = tid >> 5, d = tid & 31;
            float r  = sigmoidf_(giS[node][d] + ghS[node][d]);
            float z  = sigmoidf_(giS[node][32 + d] + ghS[node][32 + d]);
            float ng = tanhf(giS[node][64 + d] + r * ghS[node][64 + d]);
            float hold = (t > 0) ? hS[node][d] : 0.0f;
            hS[node][d] = (1.0f - z) * ng + z * hold;
        }
        __syncthreads();

        if (t < 4) {
            if (tid < 128) {   // projections for next step -> hjpS + LLC (packed)
                int node = tid >> 6, cc = tid & 63;
                int jj = blockIdx.x * 2 + node;
                const float* wr = p.mpW1 + cc * 67;
                float bj = p.b[jj];
                float si = bj * wr[65];
                float sj = bj * wr[66] + p.mpb1[cc];
                #pragma unroll
                for (int d = 0; d < 32; ++d) {
                    float hv = hS[node][d];
                    si = fmaf(hv, wr[d], si);
                    sj = fmaf(hv, wr[32 + d], sj);
                }
                hjpS[node][cc] = sj;
                float sp = __shfl(si, lane ^ 1);
                if (!(lane & 1)) {
                    unsigned pk = (unsigned)__builtin_bit_cast(unsigned short, (__bf16)si)
                                | ((unsigned)__builtin_bit_cast(unsigned short, (__bf16)sp) << 16);
                    atomicExch(&hb_next[jj * 32 + (cc >> 1)], pk);
                }
            }
            xbarrier(p.bar, (unsigned)(t + 2), blockIdx.x);
        } else {
            if (wave < 2) {   // readout
                int node = wave;
                int jj = blockIdx.x * 2 + node;
                float y1 = p.rb1[lane];
                #pragma unroll
                for (int k = 0; k < 32; ++k) y1 = fmaf(hS[node][k], p.rW1[lane * 32 + k], y1);
                y1 = fmaxf(y1, 0.0f);
                float y2 = p.rb2[lane];
                #pragma unroll
                for (int k = 0; k < 64; ++k) y2 = fmaf(__shfl(y1, k), p.rW2[lane * 64 + k], y2);
                y2 = fmaxf(y2, 0.0f);
                float y3 = (lane < 2) ? p.rb3[lane] : 0.0f;
                #pragma unroll
                for (int k = 0; k < 64; ++k) {
                    float v = __shfl(y2, k);
                    if (lane < 2) y3 = fmaf(v, p.rW3[lane * 64 + k], y3);
                }
                if (lane < 2) p.out[jj * 2 + lane] = sigmoidf_(y3);
            }
        }
    }
}

// ---------------------------------------------------------------------------
extern "C" void kernel_launch(void* const* d_in, const int* in_sizes, int n_in,
                              void* d_out, int out_size, void* d_ws, size_t ws_size,
                              hipStream_t stream)
{
    float* ws = (float*)d_ws;

    KParams p;
    p.J    = (const float*)d_in[0];
    p.b    = (const float*)d_in[1];
    p.mpW1 = (const float*)d_in[2];
    p.mpb1 = (const float*)d_in[3];
    p.mpW2 = (const float*)d_in[4];
    p.mpb2 = (const float*)d_in[5];
    p.mpW3 = (const float*)d_in[6];
    p.mpb3 = (const float*)d_in[7];
    p.Wih  = (const float*)d_in[8];
    p.Whh  = (const float*)d_in[9];
    p.bih  = (const float*)d_in[10];
    p.bhh  = (const float*)d_in[11];
    p.rW1  = (const float*)d_in[12];
    p.rb1  = (const float*)d_in[13];
    p.rW2  = (const float*)d_in[14];
    p.rb2  = (const float*)d_in[15];
    p.rW3  = (const float*)d_in[16];
    p.rb3  = (const float*)d_in[17];
    p.out  = (float*)d_out;

    p.hb0  = (unsigned*)ws;            // 512*32 u32 (packed bf16 pairs)
    p.hb1  = (unsigned*)(ws + 16384);
    p.bar  = (unsigned*)(ws + 32768);  // tree barrier state

    hipMemsetAsync(p.bar, 0, 4096, stream);

    hipFuncSetAttribute((const void*)fused_kernel,
                        hipFuncAttributeMaxDynamicSharedMemorySize, LDS_TOTAL);
    fused_kernel<<<dim3(NB), dim3(512), LDS_TOTAL, stream>>>(p);
}

// Round 9
// 174.221 us; speedup vs baseline: 3.0547x; 1.0191x over previous
//
#include <hip/hip_runtime.h>
#include <math.h>

#define NN 512     // N_NODES
#define SD 32      // STATE_DIM == MESSAGE_DIM
#define HM 64      // H_MSG
#define NB 256     // blocks
#define NGRP 16    // barrier tree groups

typedef _Float16 f16x8 __attribute__((ext_vector_type(8)));
typedef float floatx4 __attribute__((ext_vector_type(4)));
typedef unsigned uintx4 __attribute__((ext_vector_type(4)));

// ---- dynamic LDS layout (bytes) ----
#define OFF_HBS   0        // 512 rows x 144 B (packed f16 h-projections) = 73728
#define OFF_M2L   73728    // 8 waves x (16 edges x 144 B packed-f16 m2)  = 18432
#define OFF_MSUM  92160    // 8x32 f32
#define OFF_HJP   93184    // 2x64 f32
#define OFF_H     93696    // 2x32 f32
#define OFF_MSG   93952    // 2x32 f32
#define OFF_GI    94208    // 2x96 f32
#define OFF_GH    94976    // 2x96 f32
#define LDS_TOTAL 95744

struct KParams {
    const float *J, *b, *mpW1, *mpb1, *mpW2, *mpb2, *mpW3, *mpb3;
    const float *Wih, *Whh, *bih, *bhh;
    const float *rW1, *rb1, *rW2, *rb2, *rW3, *rb3;
    float *out;
    unsigned *hb0, *hb1;   // hip double buffers, packed f16 pairs (512*32 u32)
    unsigned *bar;         // tree barrier state
};

__device__ __forceinline__ float sigmoidf_(float x) {
    return 1.0f / (1.0f + __expf(-x));
}

// ---- packed f16 ops as raw VOP3P (ROCm header-independent) ----------------
__device__ __forceinline__ unsigned pkrtz(float a, float b) {
    unsigned r;
    asm("v_cvt_pkrtz_f16_f32 %0, %1, %2" : "=v"(r) : "v"(a), "v"(b));
    return r;
}
__device__ __forceinline__ unsigned pk_add(unsigned a, unsigned b) {
    unsigned r;
    asm("v_pk_add_f16 %0, %1, %2" : "=v"(r) : "v"(a), "v"(b));
    return r;
}
__device__ __forceinline__ unsigned pk_fma(unsigned a, unsigned b, unsigned c) {
    unsigned r;
    asm("v_pk_fma_f16 %0, %1, %2, %3" : "=v"(r) : "v"(a), "v"(b), "v"(c));
    return r;
}
__device__ __forceinline__ unsigned pk_relu(unsigned a) {
    unsigned r, z = 0u;
    asm("v_pk_max_f16 %0, %1, %2" : "=v"(r) : "v"(a), "v"(z));
    return r;
}

// ---- coherence-point primitives (no cache maintenance anywhere) -----------
__device__ __forceinline__ unsigned ld_bypass_u32(const unsigned* p) {
    unsigned r;
    asm volatile("global_load_dword %0, %1, off sc0 sc1\n\ts_waitcnt vmcnt(0)"
                 : "=v"(r) : "v"(p) : "memory");
    return r;
}
__device__ __forceinline__ void issue16(const unsigned* p, uintx4& d) {
    asm volatile("global_load_dwordx4 %0, %1, off sc0 sc1" : "=&v"(d) : "v"(p));
}
__device__ __forceinline__ void waitc2(uintx4& a, uintx4& b) {
    asm volatile("s_waitcnt vmcnt(2)" : "+v"(a), "+v"(b) :: "memory");
}
__device__ __forceinline__ void waitc0(uintx4& a, uintx4& b) {
    asm volatile("s_waitcnt vmcnt(0)" : "+v"(a), "+v"(b) :: "memory");
}

// Tree sense barrier (monotonic rounds, 1-based).
__device__ __forceinline__ void xbarrier(unsigned* bar, unsigned round, int bid) {
    __syncthreads();
    if (threadIdx.x == 0) {
        unsigned g = (unsigned)bid >> 4;
        unsigned old = atomicAdd(&bar[g * 16], 1u);
        if (old + 1u == round * NGRP) {
            unsigned r2 = atomicAdd(&bar[256], 1u);
            if (r2 + 1u == round * NGRP) {
                atomicMax(&bar[272], round);
            } else {
                while (ld_bypass_u32(&bar[272]) < round) __builtin_amdgcn_s_sleep(2);
            }
        } else {
            while (ld_bypass_u32(&bar[272]) < round) __builtin_amdgcn_s_sleep(2);
        }
    }
    __syncthreads();
}

// 256 blocks x 512 threads; block owns nodes 2*bid, 2*bid+1 (waves 0-3/4-7).
// Swapped-operand MFMA edge MLP (A=weights, B=activations), packed f16,
// per-wave in-order LDS transpose (no waitcnt asm), chunk-pipelined staging.
__global__ __launch_bounds__(512, 1) void fused_kernel(KParams p)
{
    extern __shared__ __align__(16) char smem[];
    char* hbS   = smem + OFF_HBS;                  // packed f16 rows, stride 144 B
    float (*msum)[32] = (float(*)[32])(smem + OFF_MSUM);
    float (*hjpS)[64] = (float(*)[64])(smem + OFF_HJP);
    float (*hS)[32]   = (float(*)[32])(smem + OFF_H);
    float (*msgS)[32] = (float(*)[32])(smem + OFF_MSG);
    float (*giS)[96]  = (float(*)[96])(smem + OFF_GI);
    float (*ghS)[96]  = (float(*)[96])(smem + OFF_GH);

    const int tid  = threadIdx.x;
    const int lane = tid & 63;
    const int wave = tid >> 6;       // 0..7
    const int nsel = wave >> 2;      // node select
    const int nw   = wave & 3;       // wave-within-node
    const int j    = blockIdx.x * 2 + nsel;
    const int q    = lane >> 4;
    const int c    = lane & 15;

    char* m2Lw = smem + OFF_M2L + wave * 2304;     // per-wave 16 edges x 144 B

    // ---------------- prep: h==0 projections, packed f16 -> LLC -----------
    if (tid < 128) {
        int node = tid >> 6, cc = tid & 63;
        int jj = blockIdx.x * 2 + node;
        const float* wr = p.mpW1 + cc * 67;
        float bj = p.b[jj];
        hjpS[node][cc] = bj * wr[66] + p.mpb1[cc];
        float si = bj * wr[65];
        float sp = __shfl(si, lane ^ 1);
        if (!(lane & 1))
            atomicExch(&p.hb0[jj * 32 + (cc >> 1)], pkrtz(si, sp));
    }

    // ---------------- persistent per-lane preloads ----------------
    unsigned wj2a[4], wj2b[4];
    #pragma unroll
    for (int i = 0; i < 4; ++i) {
        wj2a[i] = pkrtz(p.mpW1[(q * 8 + 2 * i) * 67 + 64],
                        p.mpW1[(q * 8 + 2 * i + 1) * 67 + 64]);
        wj2b[i] = pkrtz(p.mpW1[(q * 8 + 2 * i + 32) * 67 + 64],
                        p.mpW1[(q * 8 + 2 * i + 33) * 67 + 64]);
    }
    floatx4 b2i[4], b3i[2];
    #pragma unroll
    for (int t4 = 0; t4 < 4; ++t4)
        #pragma unroll
        for (int r = 0; r < 4; ++r) b2i[t4][r] = p.mpb2[t4 * 16 + q * 4 + r];
    #pragma unroll
    for (int t2 = 0; t2 < 2; ++t2)
        #pragma unroll
        for (int r = 0; r < 4; ++r) b3i[t2][r] = p.mpb3[t2 * 16 + q * 4 + r];

    // A-operand weight fragments: Aw2[f][t4][s] = W2[t4*16+c][f*32+q*8+s]
    // (same data as the R2-R7-verified B-frags; A layout A[m=lane&15][k=q*8+s])
    f16x8 Aw2[2][4], Aw3[2][2];
    #pragma unroll
    for (int f = 0; f < 2; ++f)
        #pragma unroll
        for (int t4 = 0; t4 < 4; ++t4) {
            const float* src = p.mpW2 + (t4 * 16 + c) * 64 + f * 32 + q * 8;
            #pragma unroll
            for (int s = 0; s < 8; ++s) Aw2[f][t4][s] = (_Float16)src[s];
        }
    #pragma unroll
    for (int f = 0; f < 2; ++f)
        #pragma unroll
        for (int t2 = 0; t2 < 2; ++t2) {
            const float* src = p.mpW3 + (t2 * 16 + c) * 64 + f * 32 + q * 8;
            #pragma unroll
            for (int s = 0; s < 8; ++s) Aw3[f][t2][s] = (_Float16)src[s];
        }

    // J values: wave nw handles groups {8k+nw} (jA) and {8k+4+nw} (jB)
    const float jA = p.J[((8 * (lane >> 4) + nw) * 16 + (lane & 15)) * NN + j];
    const float jB = p.J[((8 * (lane >> 4) + 4 + nw) * 16 + (lane & 15)) * NN + j];

    xbarrier(p.bar, 1, blockIdx.x);    // hb0 visible everywhere

    // ---------------- 5 message-passing steps ----------------
    for (int t = 0; t < 5; ++t) {
        const unsigned* hb_read = (t & 1) ? p.hb1 : p.hb0;
        unsigned*       hb_next = (t & 1) ? p.hb0 : p.hb1;

        // per-step hjp packed pairs
        unsigned hjp2a[4], hjp2b[4];
        #pragma unroll
        for (int i = 0; i < 4; ++i) {
            hjp2a[i] = pkrtz(hjpS[nsel][q * 8 + 2 * i], hjpS[nsel][q * 8 + 2 * i + 1]);
            hjp2b[i] = pkrtz(hjpS[nsel][q * 8 + 2 * i + 32], hjpS[nsel][q * 8 + 2 * i + 33]);
        }

        float accf[2][4];
        #pragma unroll
        for (int t2 = 0; t2 < 2; ++t2)
            #pragma unroll
            for (int r = 0; r < 4; ++r) accf[t2][r] = 0.0f;

        // ---- chunk-pipelined staging: 4 chunks of 128 rows (16 KB) ----
        uintx4 cr[4][2];
        const unsigned gbase = (unsigned)((tid >> 2) * 32 + (tid & 3) * 8);
        const unsigned lbase = (unsigned)((tid >> 2) * 144 + (tid & 3) * 32);
        #define ISSUE(k)  do { const unsigned* gp = hb_read + (k)*4096 + gbase; \
                               issue16(gp, cr[k][0]); issue16(gp + 4, cr[k][1]); } while (0)
        #define WRITE(k)  do { char* dst = hbS + (k)*128*144 + lbase; \
                               *(uintx4*)dst = cr[k][0]; *(uintx4*)(dst+16) = cr[k][1]; } while (0)
        ISSUE(0); ISSUE(1);
        waitc2(cr[0][0], cr[0][1]);
        WRITE(0);
        ISSUE(2);
        __syncthreads();

        // ---- edge group: swapped MFMA, packed f16, no waitcnt asm ----
        auto edge_group = [&](int G, float Jv) {
            const char* rb = hbS + (G * 16 + c) * 144;
            uintx4 vlo = *(const uintx4*)(rb + q * 16);
            uintx4 vhi = *(const uintx4*)(rb + 64 + q * 16);
            const unsigned Jp = pkrtz(Jv, Jv);

            uintx4 a0u, a1u;
            #pragma unroll
            for (int i = 0; i < 4; ++i) {
                a0u[i] = pk_relu(pk_fma(Jp, wj2a[i], pk_add(vlo[i], hjp2a[i])));
                a1u[i] = pk_relu(pk_fma(Jp, wj2b[i], pk_add(vhi[i], hjp2b[i])));
            }
            f16x8 B0 = __builtin_bit_cast(f16x8, a0u);
            f16x8 B1 = __builtin_bit_cast(f16x8, a1u);

            // GEMM1 (swapped): c1[t4] lane(q,c): outch=t4*16+q*4+r, edge=c
            floatx4 c1[4];
            #pragma unroll
            for (int t4 = 0; t4 < 4; ++t4) {
                c1[t4] = __builtin_amdgcn_mfma_f32_16x16x32_f16(Aw2[0][t4], B0, b2i[t4], 0, 0, 0);
                c1[t4] = __builtin_amdgcn_mfma_f32_16x16x32_f16(Aw2[1][t4], B1, c1[t4], 0, 0, 0);
            }
            // relu + pack adjacent outch pairs (in-lane) -> 4 ds_write_b64
            #pragma unroll
            for (int t4 = 0; t4 < 4; ++t4) {
                unsigned p0 = pkrtz(fmaxf(c1[t4][0], 0.f), fmaxf(c1[t4][1], 0.f));
                unsigned p1 = pkrtz(fmaxf(c1[t4][2], 0.f), fmaxf(c1[t4][3], 0.f));
                *(uint2*)(m2Lw + c * 144 + t4 * 32 + q * 8) = make_uint2(p0, p1);
            }
            // B2-frags: packed f16 channels, 2 ds_read_b128 (same-wave in-order DS)
            uintx4 rlo = *(const uintx4*)(m2Lw + c * 144 + q * 16);
            uintx4 rhi = *(const uintx4*)(m2Lw + c * 144 + 64 + q * 16);
            f16x8 B2lo = __builtin_bit_cast(f16x8, rlo);
            f16x8 B2hi = __builtin_bit_cast(f16x8, rhi);

            // GEMM2 (swapped): c2[t2] lane(q,c): outch2=t2*16+q*4+r, edge=c
            floatx4 c2[2];
            #pragma unroll
            for (int t2 = 0; t2 < 2; ++t2) {
                c2[t2] = __builtin_amdgcn_mfma_f32_16x16x32_f16(Aw3[0][t2], B2lo, b3i[t2], 0, 0, 0);
                c2[t2] = __builtin_amdgcn_mfma_f32_16x16x32_f16(Aw3[1][t2], B2hi, c2[t2], 0, 0, 0);
            }
            #pragma unroll
            for (int t2 = 0; t2 < 2; ++t2)
                #pragma unroll
                for (int r = 0; r < 4; ++r)
                    accf[t2][r] += fmaxf(c2[t2][r], 0.0f);
        };

        #pragma unroll
        for (int k = 0; k < 4; ++k) {
            edge_group(8 * k + nw,     __shfl(jA, k * 16 + c));
            edge_group(8 * k + 4 + nw, __shfl(jB, k * 16 + c));
            if (k == 0) { waitc2(cr[1][0], cr[1][1]); WRITE(1); ISSUE(3); __syncthreads(); }
            else if (k == 1) { waitc2(cr[2][0], cr[2][1]); WRITE(2); __syncthreads(); }
            else if (k == 2) { waitc0(cr[3][0], cr[3][1]); WRITE(3); __syncthreads(); }
        }
        #undef ISSUE
        #undef WRITE

        // column sums: butterfly over edge lanes c (xor 1,2,4,8 within quad)
        #pragma unroll
        for (int m = 1; m < 16; m <<= 1)
            #pragma unroll
            for (int t2 = 0; t2 < 2; ++t2)
                #pragma unroll
                for (int r = 0; r < 4; ++r)
                    accf[t2][r] += __shfl_xor(accf[t2][r], m);
        if (c == 0) {
            #pragma unroll
            for (int t2 = 0; t2 < 2; ++t2)
                #pragma unroll
                for (int r = 0; r < 4; ++r)
                    msum[wave][t2 * 16 + q * 4 + r] = accf[t2][r];
        }
        __syncthreads();

        // ---- block-local tail ----
        if (tid < 64) {
            int node = tid >> 5, d = tid & 31;
            msgS[node][d] = msum[node * 4 + 0][d] + msum[node * 4 + 1][d] +
                            msum[node * 4 + 2][d] + msum[node * 4 + 3][d];
        }
        __syncthreads();

        if (tid < 192) {
            int node = tid / 96, r = tid % 96;
            int g = r >> 5, d = r & 31;
            const float* wi = p.Wih + (g * 32 + d) * 64;
            float a  = p.bih[g * 32 + d];
            float bb = p.bhh[g * 32 + d];
            if (t > 0) {
                const float* wh = p.Whh + (g * 32 + d) * 32;
                #pragma unroll
                for (int k = 0; k < 32; ++k) {
                    float hv = hS[node][k];
                    a  = fmaf(hv, wi[k], a);
                    bb = fmaf(hv, wh[k], bb);
                }
            }
            #pragma unroll
            for (int k = 0; k < 32; ++k) a = fmaf(msgS[node][k], wi[32 + k], a);
            giS[node][r] = a; ghS[node][r] = bb;
        }
        __syncthreads();

        if (tid < 64) {
            int node = tid >> 5, d = tid & 31;
            float r  = sigmoidf_(giS[node][d] + ghS[node][d]);
            float z  = sigmoidf_(giS[node][32 + d] + ghS[node][32 + d]);
            float ng = tanhf(giS[node][64 + d] + r * ghS[node][64 + d]);
            float hold = (t > 0) ? hS[node][d] : 0.0f;
            hS[node][d] = (1.0f - z) * ng + z * hold;
        }
        __syncthreads();

        if (t < 4) {
            if (tid < 128) {   // projections for next step -> hjpS + LLC (packed f16)
                int node = tid >> 6, cc = tid & 63;
                int jj = blockIdx.x * 2 + node;
                const float* wr = p.mpW1 + cc * 67;
                float bj = p.b[jj];
                float si = bj * wr[65];
                float sj = bj * wr[66] + p.mpb1[cc];
                #pragma unroll
                for (int d = 0; d < 32; ++d) {
                    float hv = hS[node][d];
                    si = fmaf(hv, wr[d], si);
                    sj = fmaf(hv, wr[32 + d], sj);
                }
                hjpS[node][cc] = sj;
                float sp = __shfl(si, lane ^ 1);
                if (!(lane & 1))
                    atomicExch(&hb_next[jj * 32 + (cc >> 1)], pkrtz(si, sp));
            }
            xbarrier(p.bar, (unsigned)(t + 2), blockIdx.x);
        } else {
            if (wave < 2) {   // readout
                int node = wave;
                int jj = blockIdx.x * 2 + node;
                float y1 = p.rb1[lane];
                #pragma unroll
                for (int k = 0; k < 32; ++k) y1 = fmaf(hS[node][k], p.rW1[lane * 32 + k], y1);
                y1 = fmaxf(y1, 0.0f);
                float y2 = p.rb2[lane];
                #pragma unroll
                for (int k = 0; k < 64; ++k) y2 = fmaf(__shfl(y1, k), p.rW2[lane * 64 + k], y2);
                y2 = fmaxf(y2, 0.0f);
                float y3 = (lane < 2) ? p.rb3[lane] : 0.0f;
                #pragma unroll
                for (int k = 0; k < 64; ++k) {
                    float v = __shfl(y2, k);
                    if (lane < 2) y3 = fmaf(v, p.rW3[lane * 64 + k], y3);
                }
                if (lane < 2) p.out[jj * 2 + lane] = sigmoidf_(y3);
            }
        }
    }
}

// ---------------------------------------------------------------------------
extern "C" void kernel_launch(void* const* d_in, const int* in_sizes, int n_in,
                              void* d_out, int out_size, void* d_ws, size_t ws_size,
                              hipStream_t stream)
{
    float* ws = (float*)d_ws;

    KParams p;
    p.J    = (const float*)d_in[0];
    p.b    = (const float*)d_in[1];
    p.mpW1 = (const float*)d_in[2];
    p.mpb1 = (const float*)d_in[3];
    p.mpW2 = (const float*)d_in[4];
    p.mpb2 = (const float*)d_in[5];
    p.mpW3 = (const float*)d_in[6];
    p.mpb3 = (const float*)d_in[7];
    p.Wih  = (const float*)d_in[8];
    p.Whh  = (const float*)d_in[9];
    p.bih  = (const float*)d_in[10];
    p.bhh  = (const float*)d_in[11];
    p.rW1  = (const float*)d_in[12];
    p.rb1  = (const float*)d_in[13];
    p.rW2  = (const float*)d_in[14];
    p.rb2  = (const float*)d_in[15];
    p.rW3  = (const float*)d_in[16];
    p.rb3  = (const float*)d_in[17];
    p.out  = (float*)d_out;

    p.hb0  = (unsigned*)ws;            // 512*32 u32 (packed f16 pairs)
    p.hb1  = (unsigned*)(ws + 16384);
    p.bar  = (unsigned*)(ws + 32768);  // tree barrier state

    (void)hipMemsetAsync(p.bar, 0, 4096, stream);

    (void)hipFuncSetAttribute((const void*)fused_kernel,
                              hipFuncAttributeMaxDynamicSharedMemorySize, LDS_TOTAL);
    fused_kernel<<<dim3(NB), dim3(512), LDS_TOTAL, stream>>>(p);
}